// Round 1
// baseline (1156.987 us; speedup 1.0000x reference)
//
#include <hip/hip_runtime.h>
#include <math.h>

// Bayesian 2-layer LSTM (B=8192,T=100,I=24,H=64,H2=128) fully fused.
// 256 blocks x 512 threads; block owns 32 batch rows for all 100 steps.
// Weights sampled per-block into bf16 register fragments; states in LDS/regs.

typedef __attribute__((ext_vector_type(8))) short short8;   // 8 bf16
typedef __attribute__((ext_vector_type(4))) float f32x4;

#define MFMA16(a, b, c) __builtin_amdgcn_mfma_f32_16x16x32_bf16((a), (b), (c), 0, 0, 0)

struct Params {
  const float* input;
  const float* w1i[3]; const float* w1h[3]; const float* b1[3];
  const float* w2i[3]; const float* w2h[3]; const float* b2[3];
  const float* f1w[3]; const float* f1b[3];
  const float* f2w[3]; const float* f2b[3];
  const float* ow[3];  const float* ob[3];
  float* out;
};

__device__ __forceinline__ float samp(const float* const q[3], int idx) {
  // w = mu + log1p(exp(rho)) * eps   (softplus), fp32 exact-ish (init only)
  return q[0][idx] + log1pf(expf(q[1][idx])) * q[2][idx];
}

__device__ __forceinline__ short f2bf(float f) {
  unsigned u = __float_as_uint(f);
  unsigned r = (u + 0x7FFFu + ((u >> 16) & 1u)) >> 16;   // RNE
  return (short)r;
}

__device__ __forceinline__ float sigf(float x) {
  return __builtin_amdgcn_rcpf(1.0f + __builtin_amdgcn_exp2f(-1.44269504f * x));
}
__device__ __forceinline__ float tanhf_(float x) {
  // tanh(x) = 1 - 2/(1 + e^{2x})
  return 1.0f - 2.0f * __builtin_amdgcn_rcpf(1.0f + __builtin_amdgcn_exp2f(2.88539008f * x));
}

__global__ __launch_bounds__(512, 2)
void blstm_kernel(Params p)
{
  // LDS state. Row strides padded (104 / 200 shorts) -> 2-way bank aliasing (free).
  __shared__ __align__(16) short A1[32 * 104];   // [x_t(24) pad(8) | h1(64)] bf16
  __shared__ __align__(16) short A2[32 * 200];   // [h1_t(64) | h2(128)] bf16
  __shared__ __align__(16) float H2L[32 * 128];  // final h2, fp32 (head input)
  __shared__ float FC1W[1024];
  __shared__ float FC2W[64];
  __shared__ float FB1[8], FB2[8], OWs[8], OBs;
  __shared__ float X1[256], X2[256];

  const int tid  = threadIdx.x;
  const int w    = tid >> 6;        // wave 0..7
  const int l    = tid & 63;
  const int quad = l >> 4;
  const int col  = l & 15;
  const int b0   = blockIdx.x * 32; // batch base row

  const int wq = w & 3;             // layer1: n-group (16 units)
  const int mh = w >> 2;            // layer1: m-half (rows 0-15 / 16-31)
  const int v0 = w * 16;            // layer2: unit base (16 units/wave)

  // ---- sample layer-1 weight fragments into registers (48 VGPR) ----
  // W1cat[k][n]: k<24 = w1i[k], 24<=k<32 = 0 (pad), k>=32 = w1h[k-32]; n = g*64 + unit
  short8 W1f[4][3];
#pragma unroll
  for (int g = 0; g < 4; ++g)
#pragma unroll
    for (int kk = 0; kk < 3; ++kk) {
      short8 v;
#pragma unroll
      for (int j = 0; j < 8; ++j) {
        int k = kk * 32 + quad * 8 + j;
        int c = g * 64 + wq * 16 + col;
        float x = 0.0f;
        if (k < 24)       x = samp(p.w1i, k * 256 + c);
        else if (k >= 32) x = samp(p.w1h, (k - 32) * 256 + c);
        v[j] = f2bf(x);
      }
      W1f[g][kk] = v;
    }

  // ---- sample layer-2 weight fragments into registers (96 VGPR) ----
  // W2cat[k][n]: k<64 = w2i[k], else w2h[k-64]; n = g*128 + unit
  short8 W2f[4][6];
#pragma unroll
  for (int g = 0; g < 4; ++g)
#pragma unroll
    for (int kk = 0; kk < 6; ++kk) {
      short8 v;
#pragma unroll
      for (int j = 0; j < 8; ++j) {
        int k = kk * 32 + quad * 8 + j;
        int c = g * 128 + v0 + col;
        float x = (k < 64) ? samp(p.w2i, k * 512 + c) : samp(p.w2h, (k - 64) * 512 + c);
        v[j] = f2bf(x);
      }
      W2f[g][kk] = v;
    }

  float b1v[4], b2v[4];
#pragma unroll
  for (int g = 0; g < 4; ++g) b1v[g] = samp(p.b1, g * 64 + wq * 16 + col);
#pragma unroll
  for (int g = 0; g < 4; ++g) b2v[g] = samp(p.b2, g * 128 + v0 + col);

  // zero state buffers (h1=h2=0 at t=0; also zeroes the k-pad of A1)
  for (int i = tid; i < 32 * 104; i += 512) A1[i] = 0;
  for (int i = tid; i < 32 * 200; i += 512) A2[i] = 0;
  __syncthreads();

  // load x_0 -> A1 (bf16): 384 threads x float2
  if (tid < 384) {
    int e = tid * 2, r = e / 24, ii = e - r * 24;
    float2 xv = *(const float2*)(p.input + (size_t)(b0 + r) * 2400 + ii);
    unsigned pk = (unsigned)(unsigned short)f2bf(xv.x)
                | ((unsigned)(unsigned short)f2bf(xv.y) << 16);
    *(unsigned*)&A1[r * 104 + ii] = pk;
  }
  __syncthreads();

  f32x4 c1 = {0.f, 0.f, 0.f, 0.f};   // layer1 cell state (16 rows x 16 units / wave)
  f32x4 c2[2]; c2[0] = c1; c2[1] = c1; // layer2 cell state (32 rows x 16 units / wave)

  const int a1base  = (mh * 16 + col) * 104;
  const int a2base0 = col * 200;
  const int a2base1 = (16 + col) * 200;

  for (int t = 0; t < 100; ++t) {
    // prefetch x_{t+1} into regs (overlaps l1 matmul)
    float2 xv; int xr = 0, xi = 0;
    const bool do_x = (t < 99) && (tid < 384);
    if (do_x) {
      int e = tid * 2; xr = e / 24; xi = e - xr * 24;
      xv = *(const float2*)(p.input + (size_t)(b0 + xr) * 2400 + (t + 1) * 24 + xi);
    }

    // ---- layer 1: gates = [x_t | h1] @ W1cat + b1 ----
    f32x4 g1[4];
#pragma unroll
    for (int g = 0; g < 4; ++g) g1[g] = (f32x4){b1v[g], b1v[g], b1v[g], b1v[g]};
#pragma unroll
    for (int kk = 0; kk < 3; ++kk) {
      short8 a = *(const short8*)&A1[a1base + kk * 32 + quad * 8];
      g1[0] = MFMA16(a, W1f[0][kk], g1[0]);
      g1[1] = MFMA16(a, W1f[1][kk], g1[1]);
      g1[2] = MFMA16(a, W1f[2][kk], g1[2]);
      g1[3] = MFMA16(a, W1f[3][kk], g1[3]);
    }
    short hb1[4];
#pragma unroll
    for (int i = 0; i < 4; ++i) {
      float iv = sigf(g1[0][i]);
      float fv = sigf(g1[1][i]);
      float gv = tanhf_(g1[2][i]);
      float ov = sigf(g1[3][i]);
      float cn = fv * c1[i] + iv * gv;
      c1[i] = cn;
      hb1[i] = f2bf(ov * tanhf_(cn));
    }
    __syncthreads();   // B1: everyone done reading A1

    {
      int u = wq * 16 + col;
#pragma unroll
      for (int i = 0; i < 4; ++i) {
        int row = mh * 16 + quad * 4 + i;
        A1[row * 104 + 32 + u] = hb1[i];   // h1 for next step's layer1
        A2[row * 200 + u]      = hb1[i];   // h1_t for this step's layer2
      }
      if (do_x) {
        unsigned pk = (unsigned)(unsigned short)f2bf(xv.x)
                    | ((unsigned)(unsigned short)f2bf(xv.y) << 16);
        *(unsigned*)&A1[xr * 104 + xi] = pk;
      }
    }
    __syncthreads();   // B2: A2 [h1_t | h2_{t-1}] ready

    // ---- layer 2: gates = [h1_t | h2] @ W2cat + b2 ----
    f32x4 g2[2][4];
#pragma unroll
    for (int g = 0; g < 4; ++g) {
      g2[0][g] = (f32x4){b2v[g], b2v[g], b2v[g], b2v[g]};
      g2[1][g] = g2[0][g];
    }
#pragma unroll
    for (int kk = 0; kk < 6; ++kk) {
      short8 a0 = *(const short8*)&A2[a2base0 + kk * 32 + quad * 8];
      short8 a1 = *(const short8*)&A2[a2base1 + kk * 32 + quad * 8];
      g2[0][0] = MFMA16(a0, W2f[0][kk], g2[0][0]);
      g2[0][1] = MFMA16(a0, W2f[1][kk], g2[0][1]);
      g2[0][2] = MFMA16(a0, W2f[2][kk], g2[0][2]);
      g2[0][3] = MFMA16(a0, W2f[3][kk], g2[0][3]);
      g2[1][0] = MFMA16(a1, W2f[0][kk], g2[1][0]);
      g2[1][1] = MFMA16(a1, W2f[1][kk], g2[1][1]);
      g2[1][2] = MFMA16(a1, W2f[2][kk], g2[1][2]);
      g2[1][3] = MFMA16(a1, W2f[3][kk], g2[1][3]);
    }
    short hb2[2][4]; float hf2[2][4];
#pragma unroll
    for (int mi = 0; mi < 2; ++mi)
#pragma unroll
      for (int i = 0; i < 4; ++i) {
        float iv = sigf(g2[mi][0][i]);
        float fv = sigf(g2[mi][1][i]);
        float gv = tanhf_(g2[mi][2][i]);
        float ov = sigf(g2[mi][3][i]);
        float cn = fv * c2[mi][i] + iv * gv;
        c2[mi][i] = cn;
        float hv = ov * tanhf_(cn);
        hf2[mi][i] = hv;
        hb2[mi][i] = f2bf(hv);
      }
    __syncthreads();   // B3: everyone done reading A2

    {
      int u2 = v0 + col;
#pragma unroll
      for (int mi = 0; mi < 2; ++mi)
#pragma unroll
        for (int i = 0; i < 4; ++i) {
          int row = mi * 16 + quad * 4 + i;
          A2[row * 200 + 64 + u2] = hb2[mi][i];
        }
      if (t == 99) {
#pragma unroll
        for (int mi = 0; mi < 2; ++mi)
#pragma unroll
          for (int i = 0; i < 4; ++i) {
            int row = mi * 16 + quad * 4 + i;
            H2L[row * 128 + u2] = hf2[mi][i];
          }
      }
    }
  }
  __syncthreads();

  // ---- head (fp32 exact): relu(h2@fc1w.T+b) -> relu(@fc2w.T+b) -> @outw.T+b ----
  for (int i = tid; i < 1024; i += 512) FC1W[i] = samp(p.f1w, i);
  if (tid < 64)                 FC2W[tid]      = samp(p.f2w, tid);
  if (tid >= 64 && tid < 72)    FB1[tid - 64]  = samp(p.f1b, tid - 64);
  if (tid >= 72 && tid < 80)    FB2[tid - 72]  = samp(p.f2b, tid - 72);
  if (tid >= 80 && tid < 88)    OWs[tid - 80]  = samp(p.ow,  tid - 80);
  if (tid == 88)                OBs            = samp(p.ob,  0);
  __syncthreads();

  if (tid < 256) {
    int row = tid >> 3, o = tid & 7;
    float s = FB1[o];
#pragma unroll 8
    for (int k = 0; k < 128; ++k) s += H2L[row * 128 + k] * FC1W[o * 128 + k];
    X1[tid] = fmaxf(s, 0.0f);
  }
  __syncthreads();
  if (tid < 256) {
    int row = tid >> 3, o = tid & 7;
    float s = FB2[o];
#pragma unroll
    for (int k = 0; k < 8; ++k) s += X1[row * 8 + k] * FC2W[o * 8 + k];
    X2[tid] = fmaxf(s, 0.0f);
  }
  __syncthreads();
  if (tid < 32) {
    float s = OBs;
#pragma unroll
    for (int k = 0; k < 8; ++k) s += X2[tid * 8 + k] * OWs[k];
    p.out[b0 + tid] = s;
  }
}

extern "C" void kernel_launch(void* const* d_in, const int* in_sizes, int n_in,
                              void* d_out, int out_size, void* d_ws, size_t ws_size,
                              hipStream_t stream)
{
  (void)in_sizes; (void)n_in; (void)d_ws; (void)ws_size; (void)out_size;
  Params p;
  p.input = (const float*)d_in[0];
  const float** grp[12] = { p.w1i, p.w1h, p.b1, p.w2i, p.w2h, p.b2,
                            p.f1w, p.f1b, p.f2w, p.f2b, p.ow, p.ob };
  int idx = 1;
  for (int t = 0; t < 12; ++t)
    for (int j = 0; j < 3; ++j)
      grp[t][j] = (const float*)d_in[idx++];
  p.out = (float*)d_out;

  blstm_kernel<<<dim3(256), dim3(512), 0, stream>>>(p);
}

// Round 2
// 1151.369 us; speedup vs baseline: 1.0049x; 1.0049x over previous
//
#include <hip/hip_runtime.h>
#include <math.h>

// Bayesian 2-layer LSTM (B=8192,T=100,I=24,H=64,H2=128) fully fused.
// 256 blocks x 512 threads; block owns 32 batch rows for all 100 steps.
// Weights sampled per-block into bf16 register fragments; states in LDS/regs.
//
// R2: pin allocator to exactly 2 waves/EU (256 VGPR budget) via
// amdgpu_waves_per_eu(2,2). R1 showed launch_bounds(512,2) let the compiler
// target 4 waves/EU -> 128 VGPR -> spilled all weight fragments to scratch
// (FETCH 2.6 GB of spill reloads == the entire 1060 us runtime).

typedef __attribute__((ext_vector_type(8))) short short8;   // 8 bf16
typedef __attribute__((ext_vector_type(4))) float f32x4;

#define MFMA16(a, b, c) __builtin_amdgcn_mfma_f32_16x16x32_bf16((a), (b), (c), 0, 0, 0)

struct Params {
  const float* input;
  const float* w1i[3]; const float* w1h[3]; const float* b1[3];
  const float* w2i[3]; const float* w2h[3]; const float* b2[3];
  const float* f1w[3]; const float* f1b[3];
  const float* f2w[3]; const float* f2b[3];
  const float* ow[3];  const float* ob[3];
  float* out;
};

__device__ __forceinline__ float samp(const float* const q[3], int idx) {
  // w = mu + log1p(exp(rho)) * eps   (softplus), fp32 exact-ish (init only)
  return q[0][idx] + log1pf(expf(q[1][idx])) * q[2][idx];
}

__device__ __forceinline__ short f2bf(float f) {
  unsigned u = __float_as_uint(f);
  unsigned r = (u + 0x7FFFu + ((u >> 16) & 1u)) >> 16;   // RNE
  return (short)r;
}

__device__ __forceinline__ float sigf(float x) {
  return __builtin_amdgcn_rcpf(1.0f + __builtin_amdgcn_exp2f(-1.44269504f * x));
}
__device__ __forceinline__ float tanhf_(float x) {
  // tanh(x) = 1 - 2/(1 + e^{2x})
  return 1.0f - 2.0f * __builtin_amdgcn_rcpf(1.0f + __builtin_amdgcn_exp2f(2.88539008f * x));
}

__global__
__attribute__((amdgpu_flat_work_group_size(512, 512), amdgpu_waves_per_eu(2, 2)))
void blstm_kernel(Params p)
{
  // LDS state. Row strides padded (104 / 200 shorts) -> 2-way bank aliasing (free).
  __shared__ __align__(16) short A1[32 * 104];   // [x_t(24) pad(8) | h1(64)] bf16
  __shared__ __align__(16) short A2[32 * 200];   // [h1_t(64) | h2(128)] bf16
  __shared__ __align__(16) float H2L[32 * 128];  // final h2, fp32 (head input)
  __shared__ float FC1W[1024];
  __shared__ float FC2W[64];
  __shared__ float FB1[8], FB2[8], OWs[8], OBs;
  __shared__ float X1[256], X2[256];

  const int tid  = threadIdx.x;
  const int w    = tid >> 6;        // wave 0..7
  const int l    = tid & 63;
  const int quad = l >> 4;
  const int col  = l & 15;
  const int b0   = blockIdx.x * 32; // batch base row

  const int wq = w & 3;             // layer1: n-group (16 units)
  const int mh = w >> 2;            // layer1: m-half (rows 0-15 / 16-31)
  const int v0 = w * 16;            // layer2: unit base (16 units/wave)

  // ---- sample layer-1 weight fragments into registers (48 VGPR) ----
  // W1cat[k][n]: k<24 = w1i[k], 24<=k<32 = 0 (pad), k>=32 = w1h[k-32]; n = g*64 + unit
  short8 W1f[4][3];
#pragma unroll
  for (int g = 0; g < 4; ++g)
#pragma unroll
    for (int kk = 0; kk < 3; ++kk) {
      short8 v;
#pragma unroll
      for (int j = 0; j < 8; ++j) {
        int k = kk * 32 + quad * 8 + j;
        int c = g * 64 + wq * 16 + col;
        float x = 0.0f;
        if (k < 24)       x = samp(p.w1i, k * 256 + c);
        else if (k >= 32) x = samp(p.w1h, (k - 32) * 256 + c);
        v[j] = f2bf(x);
      }
      W1f[g][kk] = v;
    }

  // ---- sample layer-2 weight fragments into registers (96 VGPR) ----
  // W2cat[k][n]: k<64 = w2i[k], else w2h[k-64]; n = g*128 + unit
  short8 W2f[4][6];
#pragma unroll
  for (int g = 0; g < 4; ++g)
#pragma unroll
    for (int kk = 0; kk < 6; ++kk) {
      short8 v;
#pragma unroll
      for (int j = 0; j < 8; ++j) {
        int k = kk * 32 + quad * 8 + j;
        int c = g * 128 + v0 + col;
        float x = (k < 64) ? samp(p.w2i, k * 512 + c) : samp(p.w2h, (k - 64) * 512 + c);
        v[j] = f2bf(x);
      }
      W2f[g][kk] = v;
    }

  float b1v[4], b2v[4];
#pragma unroll
  for (int g = 0; g < 4; ++g) b1v[g] = samp(p.b1, g * 64 + wq * 16 + col);
#pragma unroll
  for (int g = 0; g < 4; ++g) b2v[g] = samp(p.b2, g * 128 + v0 + col);

  // zero state buffers (h1=h2=0 at t=0; also zeroes the k-pad of A1)
  for (int i = tid; i < 32 * 104; i += 512) A1[i] = 0;
  for (int i = tid; i < 32 * 200; i += 512) A2[i] = 0;
  __syncthreads();

  // load x_0 -> A1 (bf16): 384 threads x float2
  if (tid < 384) {
    int e = tid * 2, r = e / 24, ii = e - r * 24;
    float2 xv = *(const float2*)(p.input + (size_t)(b0 + r) * 2400 + ii);
    unsigned pk = (unsigned)(unsigned short)f2bf(xv.x)
                | ((unsigned)(unsigned short)f2bf(xv.y) << 16);
    *(unsigned*)&A1[r * 104 + ii] = pk;
  }
  __syncthreads();

  f32x4 c1 = {0.f, 0.f, 0.f, 0.f};   // layer1 cell state (16 rows x 16 units / wave)
  f32x4 c2[2]; c2[0] = c1; c2[1] = c1; // layer2 cell state (32 rows x 16 units / wave)

  const int a1base  = (mh * 16 + col) * 104;
  const int a2base0 = col * 200;
  const int a2base1 = (16 + col) * 200;

  for (int t = 0; t < 100; ++t) {
    // prefetch x_{t+1} into regs (overlaps l1 matmul)
    float2 xv; int xr = 0, xi = 0;
    const bool do_x = (t < 99) && (tid < 384);
    if (do_x) {
      int e = tid * 2; xr = e / 24; xi = e - xr * 24;
      xv = *(const float2*)(p.input + (size_t)(b0 + xr) * 2400 + (t + 1) * 24 + xi);
    }

    // ---- layer 1: gates = [x_t | h1] @ W1cat + b1 ----
    f32x4 g1[4];
#pragma unroll
    for (int g = 0; g < 4; ++g) g1[g] = (f32x4){b1v[g], b1v[g], b1v[g], b1v[g]};
#pragma unroll
    for (int kk = 0; kk < 3; ++kk) {
      short8 a = *(const short8*)&A1[a1base + kk * 32 + quad * 8];
      g1[0] = MFMA16(a, W1f[0][kk], g1[0]);
      g1[1] = MFMA16(a, W1f[1][kk], g1[1]);
      g1[2] = MFMA16(a, W1f[2][kk], g1[2]);
      g1[3] = MFMA16(a, W1f[3][kk], g1[3]);
    }
    short hb1[4];
#pragma unroll
    for (int i = 0; i < 4; ++i) {
      float iv = sigf(g1[0][i]);
      float fv = sigf(g1[1][i]);
      float gv = tanhf_(g1[2][i]);
      float ov = sigf(g1[3][i]);
      float cn = fv * c1[i] + iv * gv;
      c1[i] = cn;
      hb1[i] = f2bf(ov * tanhf_(cn));
    }
    __syncthreads();   // B1: everyone done reading A1

    {
      int u = wq * 16 + col;
#pragma unroll
      for (int i = 0; i < 4; ++i) {
        int row = mh * 16 + quad * 4 + i;
        A1[row * 104 + 32 + u] = hb1[i];   // h1 for next step's layer1
        A2[row * 200 + u]      = hb1[i];   // h1_t for this step's layer2
      }
      if (do_x) {
        unsigned pk = (unsigned)(unsigned short)f2bf(xv.x)
                    | ((unsigned)(unsigned short)f2bf(xv.y) << 16);
        *(unsigned*)&A1[xr * 104 + xi] = pk;
      }
    }
    __syncthreads();   // B2: A2 [h1_t | h2_{t-1}] ready

    // ---- layer 2: gates = [h1_t | h2] @ W2cat + b2 ----
    f32x4 g2[2][4];
#pragma unroll
    for (int g = 0; g < 4; ++g) {
      g2[0][g] = (f32x4){b2v[g], b2v[g], b2v[g], b2v[g]};
      g2[1][g] = g2[0][g];
    }
#pragma unroll
    for (int kk = 0; kk < 6; ++kk) {
      short8 a0 = *(const short8*)&A2[a2base0 + kk * 32 + quad * 8];
      short8 a1 = *(const short8*)&A2[a2base1 + kk * 32 + quad * 8];
      g2[0][0] = MFMA16(a0, W2f[0][kk], g2[0][0]);
      g2[0][1] = MFMA16(a0, W2f[1][kk], g2[0][1]);
      g2[0][2] = MFMA16(a0, W2f[2][kk], g2[0][2]);
      g2[0][3] = MFMA16(a0, W2f[3][kk], g2[0][3]);
      g2[1][0] = MFMA16(a1, W2f[0][kk], g2[1][0]);
      g2[1][1] = MFMA16(a1, W2f[1][kk], g2[1][1]);
      g2[1][2] = MFMA16(a1, W2f[2][kk], g2[1][2]);
      g2[1][3] = MFMA16(a1, W2f[3][kk], g2[1][3]);
    }
    short hb2[2][4]; float hf2[2][4];
#pragma unroll
    for (int mi = 0; mi < 2; ++mi)
#pragma unroll
      for (int i = 0; i < 4; ++i) {
        float iv = sigf(g2[mi][0][i]);
        float fv = sigf(g2[mi][1][i]);
        float gv = tanhf_(g2[mi][2][i]);
        float ov = sigf(g2[mi][3][i]);
        float cn = fv * c2[mi][i] + iv * gv;
        c2[mi][i] = cn;
        float hv = ov * tanhf_(cn);
        hf2[mi][i] = hv;
        hb2[mi][i] = f2bf(hv);
      }
    __syncthreads();   // B3: everyone done reading A2

    {
      int u2 = v0 + col;
#pragma unroll
      for (int mi = 0; mi < 2; ++mi)
#pragma unroll
        for (int i = 0; i < 4; ++i) {
          int row = mi * 16 + quad * 4 + i;
          A2[row * 200 + 64 + u2] = hb2[mi][i];
        }
      if (t == 99) {
#pragma unroll
        for (int mi = 0; mi < 2; ++mi)
#pragma unroll
          for (int i = 0; i < 4; ++i) {
            int row = mi * 16 + quad * 4 + i;
            H2L[row * 128 + u2] = hf2[mi][i];
          }
      }
    }
  }
  __syncthreads();

  // ---- head (fp32 exact): relu(h2@fc1w.T+b) -> relu(@fc2w.T+b) -> @outw.T+b ----
  for (int i = tid; i < 1024; i += 512) FC1W[i] = samp(p.f1w, i);
  if (tid < 64)                 FC2W[tid]      = samp(p.f2w, tid);
  if (tid >= 64 && tid < 72)    FB1[tid - 64]  = samp(p.f1b, tid - 64);
  if (tid >= 72 && tid < 80)    FB2[tid - 72]  = samp(p.f2b, tid - 72);
  if (tid >= 80 && tid < 88)    OWs[tid - 80]  = samp(p.ow,  tid - 80);
  if (tid == 88)                OBs            = samp(p.ob,  0);
  __syncthreads();

  if (tid < 256) {
    int row = tid >> 3, o = tid & 7;
    float s = FB1[o];
#pragma unroll 8
    for (int k = 0; k < 128; ++k) s += H2L[row * 128 + k] * FC1W[o * 128 + k];
    X1[tid] = fmaxf(s, 0.0f);
  }
  __syncthreads();
  if (tid < 256) {
    int row = tid >> 3, o = tid & 7;
    float s = FB2[o];
#pragma unroll
    for (int k = 0; k < 8; ++k) s += X1[row * 8 + k] * FC2W[o * 8 + k];
    X2[tid] = fmaxf(s, 0.0f);
  }
  __syncthreads();
  if (tid < 32) {
    float s = OBs;
#pragma unroll
    for (int k = 0; k < 8; ++k) s += X2[tid * 8 + k] * OWs[k];
    p.out[b0 + tid] = s;
  }
}

extern "C" void kernel_launch(void* const* d_in, const int* in_sizes, int n_in,
                              void* d_out, int out_size, void* d_ws, size_t ws_size,
                              hipStream_t stream)
{
  (void)in_sizes; (void)n_in; (void)d_ws; (void)ws_size; (void)out_size;
  Params p;
  p.input = (const float*)d_in[0];
  const float** grp[12] = { p.w1i, p.w1h, p.b1, p.w2i, p.w2h, p.b2,
                            p.f1w, p.f1b, p.f2w, p.f2b, p.ow, p.ob };
  int idx = 1;
  for (int t = 0; t < 12; ++t)
    for (int j = 0; j < 3; ++j)
      grp[t][j] = (const float*)d_in[idx++];
  p.out = (float*)d_out;

  blstm_kernel<<<dim3(256), dim3(512), 0, stream>>>(p);
}

// Round 3
// 1103.259 us; speedup vs baseline: 1.0487x; 1.0436x over previous
//
#include <hip/hip_runtime.h>
#include <math.h>

// Bayesian 2-layer LSTM (B=8192,T=100,I=24,H=64,H2=128) fully fused.
// 256 blocks x 512 threads; block owns 32 batch rows for all 100 steps.
//
// R3: registers were the bottleneck (R1/R2: budget 256 = 128 arch + 128 acc
// at 2 waves/EU, demand ~290 -> ~50 regs spilled, reloaded 100x = 2.6 GB
// FETCH = entire runtime). This version sheds ~80 regs:
//   - W1cat lives in LDS (48 KB, shared; was 48 VGPR/lane duplicated x2)
//   - layer-2 reads h1 from A1's h-slot (A2 holds h2 only)
//   - final h2 carried in 8 regs; head buffers alias the W1L LDS region
// Peak demand ~210 < 256 -> no spill expected.

typedef __attribute__((ext_vector_type(8))) short short8;   // 8 bf16
typedef __attribute__((ext_vector_type(4))) float f32x4;

#define MFMA16(a, b, c) __builtin_amdgcn_mfma_f32_16x16x32_bf16((a), (b), (c), 0, 0, 0)

struct Params {
  const float* input;
  const float* w1i[3]; const float* w1h[3]; const float* b1[3];
  const float* w2i[3]; const float* w2h[3]; const float* b2[3];
  const float* f1w[3]; const float* f1b[3];
  const float* f2w[3]; const float* f2b[3];
  const float* ow[3];  const float* ob[3];
  float* out;
};

__device__ __forceinline__ float samp(const float* const q[3], int idx) {
  return q[0][idx] + log1pf(expf(q[1][idx])) * q[2][idx];
}

__device__ __forceinline__ short f2bf(float f) {
  unsigned u = __float_as_uint(f);
  unsigned r = (u + 0x7FFFu + ((u >> 16) & 1u)) >> 16;   // RNE
  return (short)r;
}

__device__ __forceinline__ float sigf(float x) {
  return __builtin_amdgcn_rcpf(1.0f + __builtin_amdgcn_exp2f(-1.44269504f * x));
}
__device__ __forceinline__ float tanhf_(float x) {
  return 1.0f - 2.0f * __builtin_amdgcn_rcpf(1.0f + __builtin_amdgcn_exp2f(2.88539008f * x));
}

// LDS pool layout (loop phase):
//   [0,49152)      W1L : W1cat bf16, 3072 short8 units; unit u=(kk*4+quad)*256+n
//                        holds k = kk*32+quad*8 .. +7 for column n
//   [49152,55808)  A1  : 32 rows x 104 shorts  [x(24) | zero-pad(8) | h1(64)]
//   [55808,64512)  A2  : 32 rows x 136 shorts  [h2(128) | pad]
// Head phase (aliased over W1L region, loop finished):
//   [0,16896)      H2  : 32 x 132 fp32
//   [16896,20992)  FC1W (1024 f), [20992,21248) FC2W (64 f)
//   [21248..)      FB1(8) FB2(8) OW(8) OB(1), X1(256), X2(256)

__global__ __launch_bounds__(512, 2)
void blstm_kernel(Params p)
{
  __shared__ __align__(16) unsigned char pool[64512];
  short* const W1L = (short*)pool;
  short* const A1  = (short*)(pool + 49152);
  short* const A2  = (short*)(pool + 55808);

  const int tid  = threadIdx.x;
  const int w    = tid >> 6;
  const int l    = tid & 63;
  const int quad = l >> 4;
  const int col  = l & 15;
  const int b0   = blockIdx.x * 32;

  const int wq = w & 3;             // layer1: n-group (16 gate-cols)
  const int mh = w >> 2;            // layer1: m-half
  const int v0 = w * 16;            // layer2: unit base

  // ---- sample layer-2 weight fragments into registers (96 VGPR) ----
  short8 W2f[4][6];
#pragma unroll
  for (int g = 0; g < 4; ++g)
#pragma unroll
    for (int kk = 0; kk < 6; ++kk) {
      short8 v;
#pragma unroll
      for (int j = 0; j < 8; ++j) {
        int k = kk * 32 + quad * 8 + j;
        int c = g * 128 + v0 + col;
        float x = (k < 64) ? samp(p.w2i, k * 512 + c) : samp(p.w2h, (k - 64) * 512 + c);
        v[j] = f2bf(x);
      }
      W2f[g][kk] = v;
    }

  float b1v[4], b2v[4];
#pragma unroll
  for (int g = 0; g < 4; ++g) b1v[g] = samp(p.b1, g * 64 + wq * 16 + col);
#pragma unroll
  for (int g = 0; g < 4; ++g) b2v[g] = samp(p.b2, g * 128 + v0 + col);

  // ---- cooperatively sample W1cat -> LDS (once per block) ----
  for (int u = tid; u < 3072; u += 512) {
    int slice = u >> 8, n = u & 255;
    int k0 = (slice >> 2) * 32 + (slice & 3) * 8;
    short8 v;
#pragma unroll
    for (int j = 0; j < 8; ++j) {
      int k = k0 + j;
      float x = 0.0f;
      if (k < 24)       x = samp(p.w1i, k * 256 + n);
      else if (k >= 32) x = samp(p.w1h, (k - 32) * 256 + n);
      v[j] = f2bf(x);
    }
    *(short8*)&W1L[u * 8] = v;
  }
  for (int i = tid; i < 3328; i += 512) A1[i] = 0;
  for (int i = tid; i < 4352; i += 512) A2[i] = 0;
  __syncthreads();

  // load x_0 -> A1 (bf16)
  if (tid < 384) {
    int e = tid * 2, r = e / 24, ii = e - r * 24;
    float2 xv = *(const float2*)(p.input + (size_t)(b0 + r) * 2400 + ii);
    unsigned pk = (unsigned)(unsigned short)f2bf(xv.x)
                | ((unsigned)(unsigned short)f2bf(xv.y) << 16);
    *(unsigned*)&A1[r * 104 + ii] = pk;
  }
  __syncthreads();

  f32x4 c1 = {0.f, 0.f, 0.f, 0.f};
  f32x4 c2[2]; c2[0] = c1; c2[1] = c1;
  float hf2[2][4];                  // final-step h2 (fp32) lives here

  const int a1rd = (mh * 16 + col) * 104;

  for (int t = 0; t < 100; ++t) {
    float2 xv; int xr = 0, xi = 0;
    const bool do_x = (t < 99) && (tid < 384);
    if (do_x) {
      int e = tid * 2; xr = e / 24; xi = e - xr * 24;
      xv = *(const float2*)(p.input + (size_t)(b0 + xr) * 2400 + (t + 1) * 24 + xi);
    }

    // ---- layer 1: gates = [x_t | h1] @ W1cat + b1 ----
    short8 aA[3];
    aA[0] = *(const short8*)&A1[a1rd +      quad * 8];
    aA[1] = *(const short8*)&A1[a1rd + 32 + quad * 8];
    aA[2] = *(const short8*)&A1[a1rd + 64 + quad * 8];
    f32x4 g1[4];
#pragma unroll
    for (int g = 0; g < 4; ++g) {
      f32x4 acc = (f32x4){b1v[g], b1v[g], b1v[g], b1v[g]};
#pragma unroll
      for (int kk = 0; kk < 3; ++kk) {
        short8 bfr = *(const short8*)&W1L[(((kk * 4 + quad) << 8) + g * 64 + wq * 16 + col) * 8];
        acc = MFMA16(aA[kk], bfr, acc);
      }
      g1[g] = acc;
    }
    short hb1[4];
#pragma unroll
    for (int i = 0; i < 4; ++i) {
      float iv = sigf(g1[0][i]);
      float fv = sigf(g1[1][i]);
      float gv = tanhf_(g1[2][i]);
      float ov = sigf(g1[3][i]);
      float cn = fv * c1[i] + iv * gv;
      c1[i] = cn;
      hb1[i] = f2bf(ov * tanhf_(cn));
    }
    __syncthreads();   // B1: all A1 reads done

    {
      int u = wq * 16 + col;
#pragma unroll
      for (int i = 0; i < 4; ++i) {
        int row = mh * 16 + quad * 4 + i;
        A1[row * 104 + 32 + u] = hb1[i];   // h1_t (layer2 now + next step's l1)
      }
      if (do_x) {
        unsigned pk = (unsigned)(unsigned short)f2bf(xv.x)
                    | ((unsigned)(unsigned short)f2bf(xv.y) << 16);
        *(unsigned*)&A1[xr * 104 + xi] = pk;
      }
    }
    __syncthreads();   // B2: h1_t visible

    // ---- layer 2: gates = [h1_t | h2] @ W2cat + b2 ----
    f32x4 g2[2][4];
#pragma unroll
    for (int g = 0; g < 4; ++g) {
      g2[0][g] = (f32x4){b2v[g], b2v[g], b2v[g], b2v[g]};
      g2[1][g] = g2[0][g];
    }
#pragma unroll
    for (int kk = 0; kk < 6; ++kk) {
      short8 a0, a1f;
      if (kk < 2) {
        a0  = *(const short8*)&A1[      col  * 104 + 32 + kk * 32 + quad * 8];
        a1f = *(const short8*)&A1[(16 + col) * 104 + 32 + kk * 32 + quad * 8];
      } else {
        int o = (kk - 2) * 32 + quad * 8;
        a0  = *(const short8*)&A2[      col  * 136 + o];
        a1f = *(const short8*)&A2[(16 + col) * 136 + o];
      }
      g2[0][0] = MFMA16(a0,  W2f[0][kk], g2[0][0]);
      g2[0][1] = MFMA16(a0,  W2f[1][kk], g2[0][1]);
      g2[0][2] = MFMA16(a0,  W2f[2][kk], g2[0][2]);
      g2[0][3] = MFMA16(a0,  W2f[3][kk], g2[0][3]);
      g2[1][0] = MFMA16(a1f, W2f[0][kk], g2[1][0]);
      g2[1][1] = MFMA16(a1f, W2f[1][kk], g2[1][1]);
      g2[1][2] = MFMA16(a1f, W2f[2][kk], g2[1][2]);
      g2[1][3] = MFMA16(a1f, W2f[3][kk], g2[1][3]);
    }
    short hb2[2][4];
#pragma unroll
    for (int mi = 0; mi < 2; ++mi)
#pragma unroll
      for (int i = 0; i < 4; ++i) {
        float iv = sigf(g2[mi][0][i]);
        float fv = sigf(g2[mi][1][i]);
        float gv = tanhf_(g2[mi][2][i]);
        float ov = sigf(g2[mi][3][i]);
        float cn = fv * c2[mi][i] + iv * gv;
        c2[mi][i] = cn;
        float hv = ov * tanhf_(cn);
        hf2[mi][i] = hv;
        hb2[mi][i] = f2bf(hv);
      }
    __syncthreads();   // B3: all A2/A1 reads done

    {
      int u2 = v0 + col;
#pragma unroll
      for (int mi = 0; mi < 2; ++mi)
#pragma unroll
        for (int i = 0; i < 4; ++i) {
          int row = mi * 16 + quad * 4 + i;
          A2[row * 136 + u2] = hb2[mi][i];
        }
    }
  }
  __syncthreads();

  // ---- head (fp32), buffers aliased over W1L region ----
  float* const H2   = (float*)pool;                 // 32 x 132
  float* const FC1W = (float*)(pool + 16896);
  float* const FC2W = (float*)(pool + 20992);
  float* const FB1  = (float*)(pool + 21248);
  float* const FB2  = (float*)(pool + 21280);
  float* const OWp  = (float*)(pool + 21312);
  float* const OBp  = (float*)(pool + 21344);
  float* const X1   = (float*)(pool + 21376);
  float* const X2   = (float*)(pool + 22400);

  {
    int u2 = v0 + col;
#pragma unroll
    for (int mi = 0; mi < 2; ++mi)
#pragma unroll
      for (int i = 0; i < 4; ++i) {
        int row = mi * 16 + quad * 4 + i;
        H2[row * 132 + u2] = hf2[mi][i];
      }
  }
  for (int i = tid; i < 1024; i += 512) FC1W[i] = samp(p.f1w, i);
  if (tid < 64)               FC2W[tid]     = samp(p.f2w, tid);
  if (tid >= 64 && tid < 72)  FB1[tid - 64] = samp(p.f1b, tid - 64);
  if (tid >= 72 && tid < 80)  FB2[tid - 72] = samp(p.f2b, tid - 72);
  if (tid >= 80 && tid < 88)  OWp[tid - 80] = samp(p.ow,  tid - 80);
  if (tid == 88)              OBp[0]        = samp(p.ob,  0);
  __syncthreads();

  if (tid < 256) {
    int row = tid >> 3, o = tid & 7;
    float s = FB1[o];
#pragma unroll 8
    for (int k = 0; k < 128; ++k) s += H2[row * 132 + k] * FC1W[o * 128 + k];
    X1[tid] = fmaxf(s, 0.0f);
  }
  __syncthreads();
  if (tid < 256) {
    int row = tid >> 3, o = tid & 7;
    float s = FB2[o];
#pragma unroll
    for (int k = 0; k < 8; ++k) s += X1[row * 8 + k] * FC2W[o * 8 + k];
    X2[tid] = fmaxf(s, 0.0f);
  }
  __syncthreads();
  if (tid < 32) {
    float s = OBp[0];
#pragma unroll
    for (int k = 0; k < 8; ++k) s += X2[tid * 8 + k] * OWp[k];
    p.out[b0 + tid] = s;
  }
}

extern "C" void kernel_launch(void* const* d_in, const int* in_sizes, int n_in,
                              void* d_out, int out_size, void* d_ws, size_t ws_size,
                              hipStream_t stream)
{
  (void)in_sizes; (void)n_in; (void)d_ws; (void)ws_size; (void)out_size;
  Params p;
  p.input = (const float*)d_in[0];
  const float** grp[12] = { p.w1i, p.w1h, p.b1, p.w2i, p.w2h, p.b2,
                            p.f1w, p.f1b, p.f2w, p.f2b, p.ow, p.ob };
  int idx = 1;
  for (int t = 0; t < 12; ++t)
    for (int j = 0; j < 3; ++j)
      grp[t][j] = (const float*)d_in[idx++];
  p.out = (float*)d_out;

  blstm_kernel<<<dim3(256), dim3(512), 0, stream>>>(p);
}

// Round 4
// 525.134 us; speedup vs baseline: 2.2032x; 2.1009x over previous
//
#include <hip/hip_runtime.h>
#include <math.h>

// Bayesian 2-layer LSTM (B=8192,T=100,I=24,H=64,H2=128) — two-kernel version.
//
// R4: R1-R3 all lost to register spill: W2's per-thread residency (96 VGPRs,
// irreducible = 98304 el / 512 lanes) exceeds the budget the compiler insists
// on (64-128 arch regs; it ignored launch_bounds/waves_per_eu in R1-R3 and
// spilled ~90-160 regs -> 2.5 GB/dispatch scratch reloads = entire runtime).
// Fix: don't keep W2 in registers at all.
//   kernel 1 (sample_kernel): sample weights once -> d_ws, W2 pre-packed in
//     per-(kk,gate) fragment stream order (16 B/lane coalesced), W1 in the
//     LDS-linear layout, biases/head fp32.
//   kernel 2 (blstm_kernel): layer-2 K-loop streams W2 frags from L2 each
//     step (192 KB, L2-resident); live W2 regs = 16-32 transient instead of
//     96 persistent. Layer-1 weights stay in LDS (48 KB). Numerics identical
//     to R3 (absmax 4.9e-4).

typedef __attribute__((ext_vector_type(8))) short short8;   // 8 bf16
typedef __attribute__((ext_vector_type(4))) float f32x4;

#define MFMA16(a, b, c) __builtin_amdgcn_mfma_f32_16x16x32_bf16((a), (b), (c), 0, 0, 0)

// ---- d_ws layout (bytes) ----
// [0, 196608)        W2S : 12288 short8 frags, idx = (kk*4+g)*512 + tid
// [196608, 245760)   W1G : 3072 short8, u = slice*256+n (slice = kk*4+quad)
// [245760, 253284)   WF  : 1881 floats: b1[256] b2[512] fc1w[1024] fc2w[64]
//                          fc1b[8] fc2b[8] ow[8] ob[1]
#define WS_W1G_OFF 196608
#define WS_WF_OFF  245760

struct SampParams {
  const float* w1i[3]; const float* w1h[3]; const float* b1[3];
  const float* w2i[3]; const float* w2h[3]; const float* b2[3];
  const float* f1w[3]; const float* f1b[3];
  const float* f2w[3]; const float* f2b[3];
  const float* ow[3];  const float* ob[3];
  short* W2S; short* W1G; float* WF;
};

struct LstmParams {
  const float* input;
  const short* W2S; const short* W1G; const float* WF;
  float* out;
};

__device__ __forceinline__ float samp(const float* const q[3], int idx) {
  return q[0][idx] + log1pf(expf(q[1][idx])) * q[2][idx];
}

__device__ __forceinline__ short f2bf(float f) {
  unsigned u = __float_as_uint(f);
  unsigned r = (u + 0x7FFFu + ((u >> 16) & 1u)) >> 16;   // RNE
  return (short)r;
}

__device__ __forceinline__ float sigf(float x) {
  return __builtin_amdgcn_rcpf(1.0f + __builtin_amdgcn_exp2f(-1.44269504f * x));
}
__device__ __forceinline__ float tanhf_(float x) {
  return 1.0f - 2.0f * __builtin_amdgcn_rcpf(1.0f + __builtin_amdgcn_exp2f(2.88539008f * x));
}

// ---------------- kernel 1: sample all weights into d_ws ----------------
__global__ __launch_bounds__(256) void sample_kernel(SampParams p)
{
  int i = blockIdx.x * 256 + threadIdx.x;
  if (i < 12288) {
    // W2 fragment stream: i = (kk*4+g)*512 + tid
    int tid = i & 511, gg = (i >> 9) & 3, kk = i >> 11;
    int quad = (tid >> 4) & 3, col = tid & 15, v0 = (tid >> 6) * 16;
    int c = gg * 128 + v0 + col;
    short8 v;
#pragma unroll
    for (int j = 0; j < 8; ++j) {
      int k = kk * 32 + quad * 8 + j;
      float x = (k < 64) ? samp(p.w2i, k * 512 + c) : samp(p.w2h, (k - 64) * 512 + c);
      v[j] = f2bf(x);
    }
    *(short8*)&p.W2S[i * 8] = v;
  } else if (i < 15360) {
    // W1 in LDS-linear layout: u = slice*256+n, k = (slice>>2)*32+(slice&3)*8+j
    int u = i - 12288;
    int slice = u >> 8, n = u & 255;
    int k0 = (slice >> 2) * 32 + (slice & 3) * 8;
    short8 v;
#pragma unroll
    for (int j = 0; j < 8; ++j) {
      int k = k0 + j;
      float x = 0.0f;
      if (k < 24)       x = samp(p.w1i, k * 256 + n);
      else if (k >= 32) x = samp(p.w1h, (k - 32) * 256 + n);
      v[j] = f2bf(x);
    }
    *(short8*)&p.W1G[u * 8] = v;
  } else if (i < 17241) {
    int u = i - 15360;
    float x;
    if (u < 256)       x = samp(p.b1,  u);
    else if (u < 768)  x = samp(p.b2,  u - 256);
    else if (u < 1792) x = samp(p.f1w, u - 768);
    else if (u < 1856) x = samp(p.f2w, u - 1792);
    else if (u < 1864) x = samp(p.f1b, u - 1856);
    else if (u < 1872) x = samp(p.f2b, u - 1864);
    else if (u < 1880) x = samp(p.ow,  u - 1872);
    else               x = samp(p.ob,  0);
    p.WF[u] = x;
  }
}

// ---------------- kernel 2: fused 2-layer LSTM + head ----------------
// LDS pool:
//   [0,49152)      W1L : W1cat bf16 (3072 short8)
//   [49152,55808)  A1  : 32 x 104 shorts [x(24)|pad(8)|h1(64)]
//   [55808,64512)  A2  : 32 x 136 shorts [h2(128)|pad]
// Head phase aliases [0,...) : H2 32x132 f32, FC1W, FC2W, FB1/FB2/OW/OB, X1, X2

__global__ __launch_bounds__(512, 2)
void blstm_kernel(LstmParams p)
{
  __shared__ __align__(16) unsigned char pool[64512];
  short* const W1L = (short*)pool;
  short* const A1  = (short*)(pool + 49152);
  short* const A2  = (short*)(pool + 55808);

  const int tid  = threadIdx.x;
  const int w    = tid >> 6;
  const int l    = tid & 63;
  const int quad = l >> 4;
  const int col  = l & 15;
  const int b0   = blockIdx.x * 32;

  const int wq = w & 3;             // layer1: n-group
  const int mh = w >> 2;            // layer1: m-half
  const int v0 = w * 16;            // layer2: unit base

  // W1 global -> LDS (48 KB)
#pragma unroll
  for (int r = 0; r < 6; ++r) {
    short8 v = *(const short8*)&p.W1G[(r * 512 + tid) * 8];
    *(short8*)&W1L[(r * 512 + tid) * 8] = v;
  }

  float b1v[4], b2v[4];
#pragma unroll
  for (int g = 0; g < 4; ++g) b1v[g] = p.WF[g * 64 + wq * 16 + col];
#pragma unroll
  for (int g = 0; g < 4; ++g) b2v[g] = p.WF[256 + g * 128 + v0 + col];

  for (int i = tid; i < 3328; i += 512) A1[3072 * 16 / 2 * 0 + 49152 / 2 * 0 + i] = 0; // A1 zero
  for (int i = tid; i < 4352; i += 512) A2[i] = 0;
  __syncthreads();

  // x_0 -> A1
  if (tid < 384) {
    int e = tid * 2, r = e / 24, ii = e - r * 24;
    float2 xv = *(const float2*)(p.input + (size_t)(b0 + r) * 2400 + ii);
    unsigned pk = (unsigned)(unsigned short)f2bf(xv.x)
                | ((unsigned)(unsigned short)f2bf(xv.y) << 16);
    *(unsigned*)&A1[r * 104 + ii] = pk;
  }
  __syncthreads();

  f32x4 c1 = {0.f, 0.f, 0.f, 0.f};
  f32x4 c2[2]; c2[0] = c1; c2[1] = c1;
  float hf2[2][4];

  const int a1rd = (mh * 16 + col) * 104;
  const short8* const W2v = (const short8*)p.W2S;

  for (int t = 0; t < 100; ++t) {
    float2 xv; int xr = 0, xi = 0;
    const bool do_x = (t < 99) && (tid < 384);
    if (do_x) {
      int e = tid * 2; xr = e / 24; xi = e - xr * 24;
      xv = *(const float2*)(p.input + (size_t)(b0 + xr) * 2400 + (t + 1) * 24 + xi);
    }

    // ---- layer 1: gates = [x_t | h1] @ W1cat + b1 ----
    short8 aA[3];
    aA[0] = *(const short8*)&A1[a1rd +      quad * 8];
    aA[1] = *(const short8*)&A1[a1rd + 32 + quad * 8];
    aA[2] = *(const short8*)&A1[a1rd + 64 + quad * 8];
    f32x4 g1[4];
#pragma unroll
    for (int g = 0; g < 4; ++g) {
      f32x4 acc = (f32x4){b1v[g], b1v[g], b1v[g], b1v[g]};
#pragma unroll
      for (int kk = 0; kk < 3; ++kk) {
        short8 bfr = *(const short8*)&W1L[(((kk * 4 + quad) << 8) + g * 64 + wq * 16 + col) * 8];
        acc = MFMA16(aA[kk], bfr, acc);
      }
      g1[g] = acc;
    }
    short hb1[4];
#pragma unroll
    for (int i = 0; i < 4; ++i) {
      float iv = sigf(g1[0][i]);
      float fv = sigf(g1[1][i]);
      float gv = tanhf_(g1[2][i]);
      float ov = sigf(g1[3][i]);
      float cn = fv * c1[i] + iv * gv;
      c1[i] = cn;
      hb1[i] = f2bf(ov * tanhf_(cn));
    }
    __syncthreads();   // B1: all A1 reads done

    {
      int u = wq * 16 + col;
#pragma unroll
      for (int i = 0; i < 4; ++i) {
        int row = mh * 16 + quad * 4 + i;
        A1[row * 104 + 32 + u] = hb1[i];
      }
      if (do_x) {
        unsigned pk = (unsigned)(unsigned short)f2bf(xv.x)
                    | ((unsigned)(unsigned short)f2bf(xv.y) << 16);
        *(unsigned*)&A1[xr * 104 + xi] = pk;
      }
    }
    __syncthreads();   // B2: h1_t visible

    // ---- layer 2: gates = [h1_t | h2] @ W2cat + b2, W2 streamed from L2 ----
    f32x4 g2[2][4];
#pragma unroll
    for (int g = 0; g < 4; ++g) {
      g2[0][g] = (f32x4){b2v[g], b2v[g], b2v[g], b2v[g]};
      g2[1][g] = g2[0][g];
    }
#pragma unroll
    for (int kk = 0; kk < 6; ++kk) {
      short8 w0 = W2v[(kk * 4 + 0) * 512 + tid];
      short8 w1 = W2v[(kk * 4 + 1) * 512 + tid];
      short8 w2 = W2v[(kk * 4 + 2) * 512 + tid];
      short8 w3 = W2v[(kk * 4 + 3) * 512 + tid];
      short8 a0, a1f;
      if (kk < 2) {
        a0  = *(const short8*)&A1[      col  * 104 + 32 + kk * 32 + quad * 8];
        a1f = *(const short8*)&A1[(16 + col) * 104 + 32 + kk * 32 + quad * 8];
      } else {
        int o = (kk - 2) * 32 + quad * 8;
        a0  = *(const short8*)&A2[      col  * 136 + o];
        a1f = *(const short8*)&A2[(16 + col) * 136 + o];
      }
      g2[0][0] = MFMA16(a0,  w0, g2[0][0]);
      g2[0][1] = MFMA16(a0,  w1, g2[0][1]);
      g2[0][2] = MFMA16(a0,  w2, g2[0][2]);
      g2[0][3] = MFMA16(a0,  w3, g2[0][3]);
      g2[1][0] = MFMA16(a1f, w0, g2[1][0]);
      g2[1][1] = MFMA16(a1f, w1, g2[1][1]);
      g2[1][2] = MFMA16(a1f, w2, g2[1][2]);
      g2[1][3] = MFMA16(a1f, w3, g2[1][3]);
    }
    short hb2[2][4];
#pragma unroll
    for (int mi = 0; mi < 2; ++mi)
#pragma unroll
      for (int i = 0; i < 4; ++i) {
        float iv = sigf(g2[mi][0][i]);
        float fv = sigf(g2[mi][1][i]);
        float gv = tanhf_(g2[mi][2][i]);
        float ov = sigf(g2[mi][3][i]);
        float cn = fv * c2[mi][i] + iv * gv;
        c2[mi][i] = cn;
        float hv = ov * tanhf_(cn);
        hf2[mi][i] = hv;
        hb2[mi][i] = f2bf(hv);
      }
    __syncthreads();   // B3: all A2/A1 reads done

    {
      int u2 = v0 + col;
#pragma unroll
      for (int mi = 0; mi < 2; ++mi)
#pragma unroll
        for (int i = 0; i < 4; ++i) {
          int row = mi * 16 + quad * 4 + i;
          A2[row * 136 + u2] = hb2[mi][i];
        }
    }
  }
  __syncthreads();

  // ---- head (fp32), aliased over W1L region ----
  float* const H2   = (float*)pool;                 // 32 x 132
  float* const FC1W = (float*)(pool + 16896);
  float* const FC2W = (float*)(pool + 20992);
  float* const FB1  = (float*)(pool + 21248);
  float* const FB2  = (float*)(pool + 21280);
  float* const OWp  = (float*)(pool + 21312);
  float* const OBp  = (float*)(pool + 21344);
  float* const X1   = (float*)(pool + 21376);
  float* const X2   = (float*)(pool + 22400);

  {
    int u2 = v0 + col;
#pragma unroll
    for (int mi = 0; mi < 2; ++mi)
#pragma unroll
      for (int i = 0; i < 4; ++i) {
        int row = mi * 16 + quad * 4 + i;
        H2[row * 132 + u2] = hf2[mi][i];
      }
  }
  for (int i = tid; i < 1024; i += 512) FC1W[i] = p.WF[768 + i];
  if (tid < 64)               FC2W[tid]     = p.WF[1792 + tid];
  if (tid >= 64 && tid < 72)  FB1[tid - 64] = p.WF[1856 + tid - 64];
  if (tid >= 72 && tid < 80)  FB2[tid - 72] = p.WF[1864 + tid - 72];
  if (tid >= 80 && tid < 88)  OWp[tid - 80] = p.WF[1872 + tid - 80];
  if (tid == 88)              OBp[0]        = p.WF[1880];
  __syncthreads();

  if (tid < 256) {
    int row = tid >> 3, o = tid & 7;
    float s = FB1[o];
#pragma unroll 8
    for (int k = 0; k < 128; ++k) s += H2[row * 132 + k] * FC1W[o * 128 + k];
    X1[tid] = fmaxf(s, 0.0f);
  }
  __syncthreads();
  if (tid < 256) {
    int row = tid >> 3, o = tid & 7;
    float s = FB2[o];
#pragma unroll
    for (int k = 0; k < 8; ++k) s += X1[row * 8 + k] * FC2W[o * 8 + k];
    X2[tid] = fmaxf(s, 0.0f);
  }
  __syncthreads();
  if (tid < 32) {
    float s = OBp[0];
#pragma unroll
    for (int k = 0; k < 8; ++k) s += X2[tid * 8 + k] * OWp[k];
    p.out[b0 + tid] = s;
  }
}

extern "C" void kernel_launch(void* const* d_in, const int* in_sizes, int n_in,
                              void* d_out, int out_size, void* d_ws, size_t ws_size,
                              hipStream_t stream)
{
  (void)in_sizes; (void)n_in; (void)ws_size; (void)out_size;

  SampParams sp;
  const float** grp[12] = { sp.w1i, sp.w1h, sp.b1, sp.w2i, sp.w2h, sp.b2,
                            sp.f1w, sp.f1b, sp.f2w, sp.f2b, sp.ow, sp.ob };
  int idx = 1;
  for (int t = 0; t < 12; ++t)
    for (int j = 0; j < 3; ++j)
      grp[t][j] = (const float*)d_in[idx++];
  sp.W2S = (short*)d_ws;
  sp.W1G = (short*)((char*)d_ws + WS_W1G_OFF);
  sp.WF  = (float*)((char*)d_ws + WS_WF_OFF);

  LstmParams bp;
  bp.input = (const float*)d_in[0];
  bp.W2S = (const short*)d_ws;
  bp.W1G = (const short*)((char*)d_ws + WS_W1G_OFF);
  bp.WF  = (const float*)((char*)d_ws + WS_WF_OFF);
  bp.out = (float*)d_out;

  sample_kernel<<<dim3(68), dim3(256), 0, stream>>>(sp);
  blstm_kernel<<<dim3(256), dim3(512), 0, stream>>>(bp);
}

// Round 5
// 492.883 us; speedup vs baseline: 2.3474x; 1.0654x over previous
//
#include <hip/hip_runtime.h>
#include <math.h>

// Bayesian 2-layer LSTM (B=8192,T=100,I=24,H=64,H2=128) — two-kernel version.
//
// R5: merged-pipeline loop. R4 profile: MFMA 2330 cyc/step/CU (21%), VALU 44%,
// ~35-55% idle at 3 per-step barriers (1 block/CU -> all waves drain together).
// Iteration j computes gates1_j ([x_j|h1_{j-1}]) AND gates2_{j-1}
// ([h1_{j-1}|h2_{j-2}]) in ONE read segment (both read prev-iteration state
// only), then 1 barrier, tiny write segment (h1_j, h2_{j-1}, x_{j+1}),
// 1 barrier. 202 barriers vs 300, 2x ILP per segment. x-addressing hoisted.
// W2 streamed from L2 as in R4 (no persistent-reg spill).

typedef __attribute__((ext_vector_type(8))) short short8;   // 8 bf16
typedef __attribute__((ext_vector_type(4))) float f32x4;

#define MFMA16(a, b, c) __builtin_amdgcn_mfma_f32_16x16x32_bf16((a), (b), (c), 0, 0, 0)

// ---- d_ws layout (bytes) ----
// [0, 196608)        W2S : 12288 short8 frags, idx = (kk*4+g)*512 + tid
// [196608, 245760)   W1G : 3072 short8, u = slice*256+n (slice = kk*4+quad)
// [245760, 253284)   WF  : 1881 floats: b1[256] b2[512] fc1w[1024] fc2w[64]
//                          fc1b[8] fc2b[8] ow[8] ob[1]
#define WS_W1G_OFF 196608
#define WS_WF_OFF  245760

struct SampParams {
  const float* w1i[3]; const float* w1h[3]; const float* b1[3];
  const float* w2i[3]; const float* w2h[3]; const float* b2[3];
  const float* f1w[3]; const float* f1b[3];
  const float* f2w[3]; const float* f2b[3];
  const float* ow[3];  const float* ob[3];
  short* W2S; short* W1G; float* WF;
};

struct LstmParams {
  const float* input;
  const short* W2S; const short* W1G; const float* WF;
  float* out;
};

__device__ __forceinline__ float samp(const float* const q[3], int idx) {
  return q[0][idx] + log1pf(expf(q[1][idx])) * q[2][idx];
}

__device__ __forceinline__ short f2bf(float f) {
  unsigned u = __float_as_uint(f);
  unsigned r = (u + 0x7FFFu + ((u >> 16) & 1u)) >> 16;   // RNE
  return (short)r;
}

__device__ __forceinline__ float sigf(float x) {
  return __builtin_amdgcn_rcpf(1.0f + __builtin_amdgcn_exp2f(-1.44269504f * x));
}
__device__ __forceinline__ float tanhf_(float x) {
  return 1.0f - 2.0f * __builtin_amdgcn_rcpf(1.0f + __builtin_amdgcn_exp2f(2.88539008f * x));
}

// ---------------- kernel 1: sample all weights into d_ws ----------------
__global__ __launch_bounds__(256) void sample_kernel(SampParams p)
{
  int i = blockIdx.x * 256 + threadIdx.x;
  if (i < 12288) {
    int tid = i & 511, gg = (i >> 9) & 3, kk = i >> 11;
    int quad = (tid >> 4) & 3, col = tid & 15, v0 = (tid >> 6) * 16;
    int c = gg * 128 + v0 + col;
    short8 v;
#pragma unroll
    for (int j = 0; j < 8; ++j) {
      int k = kk * 32 + quad * 8 + j;
      float x = (k < 64) ? samp(p.w2i, k * 512 + c) : samp(p.w2h, (k - 64) * 512 + c);
      v[j] = f2bf(x);
    }
    *(short8*)&p.W2S[i * 8] = v;
  } else if (i < 15360) {
    int u = i - 12288;
    int slice = u >> 8, n = u & 255;
    int k0 = (slice >> 2) * 32 + (slice & 3) * 8;
    short8 v;
#pragma unroll
    for (int j = 0; j < 8; ++j) {
      int k = k0 + j;
      float x = 0.0f;
      if (k < 24)       x = samp(p.w1i, k * 256 + n);
      else if (k >= 32) x = samp(p.w1h, (k - 32) * 256 + n);
      v[j] = f2bf(x);
    }
    *(short8*)&p.W1G[u * 8] = v;
  } else if (i < 17241) {
    int u = i - 15360;
    float x;
    if (u < 256)       x = samp(p.b1,  u);
    else if (u < 768)  x = samp(p.b2,  u - 256);
    else if (u < 1792) x = samp(p.f1w, u - 768);
    else if (u < 1856) x = samp(p.f2w, u - 1792);
    else if (u < 1864) x = samp(p.f1b, u - 1856);
    else if (u < 1872) x = samp(p.f2b, u - 1864);
    else if (u < 1880) x = samp(p.ow,  u - 1872);
    else               x = samp(p.ob,  0);
    p.WF[u] = x;
  }
}

// ---------------- kernel 2: fused 2-layer LSTM + head ----------------
// LDS pool:
//   [0,49152)      W1L : W1cat bf16 (3072 short8)
//   [49152,55808)  A1  : 32 x 104 shorts [x(24)|pad(8)|h1(64)]
//   [55808,64512)  A2  : 32 x 136 shorts [h2(128)|pad]
// Head phase aliases [0,...) : H2 32x132 f32, FC1W, FC2W, FB1/FB2/OW/OB, X1, X2

__global__ __launch_bounds__(512, 2)
void blstm_kernel(LstmParams p)
{
  __shared__ __align__(16) unsigned char pool[64512];
  short* const W1L = (short*)pool;
  short* const A1  = (short*)(pool + 49152);
  short* const A2  = (short*)(pool + 55808);

  const int tid  = threadIdx.x;
  const int w    = tid >> 6;
  const int l    = tid & 63;
  const int quad = l >> 4;
  const int col  = l & 15;
  const int b0   = blockIdx.x * 32;

  const int wq = w & 3;             // layer1: n-group
  const int mh = w >> 2;            // layer1: m-half
  const int v0 = w * 16;            // layer2: unit base

  // W1 global -> LDS (48 KB)
#pragma unroll
  for (int r = 0; r < 6; ++r) {
    short8 v = *(const short8*)&p.W1G[(r * 512 + tid) * 8];
    *(short8*)&W1L[(r * 512 + tid) * 8] = v;
  }

  float b1v[4], b2v[4];
#pragma unroll
  for (int g = 0; g < 4; ++g) b1v[g] = p.WF[g * 64 + wq * 16 + col];
#pragma unroll
  for (int g = 0; g < 4; ++g) b2v[g] = p.WF[256 + g * 128 + v0 + col];

  for (int i = tid; i < 3328; i += 512) A1[i] = 0;
  for (int i = tid; i < 4352; i += 512) A2[i] = 0;
  __syncthreads();

  // x_0 -> A1; hoisted per-thread x addressing (xr,xi loop-invariant)
  int xr = 0, xi = 0;
  const float* xptr = p.input;
  if (tid < 384) {
    int e = tid * 2; xr = e / 24; xi = e - xr * 24;
    const float* base = p.input + (size_t)(b0 + xr) * 2400 + xi;
    float2 xv = *(const float2*)base;
    unsigned pk = (unsigned)(unsigned short)f2bf(xv.x)
                | ((unsigned)(unsigned short)f2bf(xv.y) << 16);
    *(unsigned*)&A1[xr * 104 + xi] = pk;
    xptr = base + 24;                 // -> x_1
  }
  __syncthreads();

  f32x4 c1 = {0.f, 0.f, 0.f, 0.f};
  f32x4 c2[2]; c2[0] = c1; c2[1] = c1;
  float hf2[2][4];

  const int a1rd = (mh * 16 + col) * 104;
  const short8* const W2v = (const short8*)p.W2S;

  // Iteration j (j=0..100): computes h1_j (layer1 on [x_j|h1_{j-1}]) and
  // h2_{j-1} (layer2 on [h1_{j-1}|h2_{j-2}]). l2 state update skipped at j=0.
  for (int j = 0; j <= 100; ++j) {
    const bool do_x = (j <= 98) && (tid < 384);
    float2 xv;
    if (do_x) xv = *(const float2*)xptr;   // x_{j+1}

    // ---- layer 1 matmul: gates1_j ----
    short8 aA0 = *(const short8*)&A1[a1rd +      quad * 8];
    short8 aA1 = *(const short8*)&A1[a1rd + 32 + quad * 8];
    short8 aA2 = *(const short8*)&A1[a1rd + 64 + quad * 8];
    f32x4 g1[4];
#pragma unroll
    for (int g = 0; g < 4; ++g) {
      f32x4 acc = (f32x4){b1v[g], b1v[g], b1v[g], b1v[g]};
      acc = MFMA16(aA0, *(const short8*)&W1L[(((0 * 4 + quad) << 8) + g * 64 + wq * 16 + col) * 8], acc);
      acc = MFMA16(aA1, *(const short8*)&W1L[(((1 * 4 + quad) << 8) + g * 64 + wq * 16 + col) * 8], acc);
      acc = MFMA16(aA2, *(const short8*)&W1L[(((2 * 4 + quad) << 8) + g * 64 + wq * 16 + col) * 8], acc);
      g1[g] = acc;
    }

    // ---- layer 2 matmul: gates2_{j-1} ----
    f32x4 g2[2][4];
#pragma unroll
    for (int g = 0; g < 4; ++g) {
      g2[0][g] = (f32x4){b2v[g], b2v[g], b2v[g], b2v[g]};
      g2[1][g] = g2[0][g];
    }
#pragma unroll
    for (int kk = 0; kk < 6; ++kk) {
      short8 w0 = W2v[(kk * 4 + 0) * 512 + tid];
      short8 w1 = W2v[(kk * 4 + 1) * 512 + tid];
      short8 w2 = W2v[(kk * 4 + 2) * 512 + tid];
      short8 w3 = W2v[(kk * 4 + 3) * 512 + tid];
      short8 a0, a1f;
      if (kk < 2) {
        a0  = *(const short8*)&A1[      col  * 104 + 32 + kk * 32 + quad * 8];
        a1f = *(const short8*)&A1[(16 + col) * 104 + 32 + kk * 32 + quad * 8];
      } else {
        int o = (kk - 2) * 32 + quad * 8;
        a0  = *(const short8*)&A2[      col  * 136 + o];
        a1f = *(const short8*)&A2[(16 + col) * 136 + o];
      }
      g2[0][0] = MFMA16(a0,  w0, g2[0][0]);
      g2[0][1] = MFMA16(a0,  w1, g2[0][1]);
      g2[0][2] = MFMA16(a0,  w2, g2[0][2]);
      g2[0][3] = MFMA16(a0,  w3, g2[0][3]);
      g2[1][0] = MFMA16(a1f, w0, g2[1][0]);
      g2[1][1] = MFMA16(a1f, w1, g2[1][1]);
      g2[1][2] = MFMA16(a1f, w2, g2[1][2]);
      g2[1][3] = MFMA16(a1f, w3, g2[1][3]);
    }

    // ---- pointwise layer 1 -> h1_j ----
    short hb1[4];
#pragma unroll
    for (int i = 0; i < 4; ++i) {
      float iv = sigf(g1[0][i]);
      float fv = sigf(g1[1][i]);
      float gv = tanhf_(g1[2][i]);
      float ov = sigf(g1[3][i]);
      float cn = fv * c1[i] + iv * gv;
      c1[i] = cn;
      hb1[i] = f2bf(ov * tanhf_(cn));
    }

    // ---- pointwise layer 2 -> h2_{j-1} (skip j=0) ----
    short hb2[2][4];
    if (j) {
#pragma unroll
      for (int mi = 0; mi < 2; ++mi)
#pragma unroll
        for (int i = 0; i < 4; ++i) {
          float iv = sigf(g2[mi][0][i]);
          float fv = sigf(g2[mi][1][i]);
          float gv = tanhf_(g2[mi][2][i]);
          float ov = sigf(g2[mi][3][i]);
          float cn = fv * c2[mi][i] + iv * gv;
          c2[mi][i] = cn;
          float hv = ov * tanhf_(cn);
          hf2[mi][i] = hv;
          hb2[mi][i] = f2bf(hv);
        }
    }
    __syncthreads();   // B1: all reads of A1/A2 done

    // ---- write segment: h1_j, h2_{j-1}, x_{j+1} ----
    {
      int u = wq * 16 + col;
#pragma unroll
      for (int i = 0; i < 4; ++i) {
        int row = mh * 16 + quad * 4 + i;
        A1[row * 104 + 32 + u] = hb1[i];
      }
      if (do_x) {
        unsigned pk = (unsigned)(unsigned short)f2bf(xv.x)
                    | ((unsigned)(unsigned short)f2bf(xv.y) << 16);
        *(unsigned*)&A1[xr * 104 + xi] = pk;
      }
      if (j) {
        int u2 = v0 + col;
#pragma unroll
        for (int mi = 0; mi < 2; ++mi)
#pragma unroll
          for (int i = 0; i < 4; ++i) {
            int row = mi * 16 + quad * 4 + i;
            A2[row * 136 + u2] = hb2[mi][i];
          }
      }
    }
    __syncthreads();   // B2: new state visible
    xptr += 24;
  }

  // ---- head (fp32), aliased over W1L region ----
  float* const H2   = (float*)pool;                 // 32 x 132
  float* const FC1W = (float*)(pool + 16896);
  float* const FC2W = (float*)(pool + 20992);
  float* const FB1  = (float*)(pool + 21248);
  float* const FB2  = (float*)(pool + 21280);
  float* const OWp  = (float*)(pool + 21312);
  float* const OBp  = (float*)(pool + 21344);
  float* const X1   = (float*)(pool + 21376);
  float* const X2   = (float*)(pool + 22400);

  {
    int u2 = v0 + col;
#pragma unroll
    for (int mi = 0; mi < 2; ++mi)
#pragma unroll
      for (int i = 0; i < 4; ++i) {
        int row = mi * 16 + quad * 4 + i;
        H2[row * 132 + u2] = hf2[mi][i];   // h2_99
      }
  }
  for (int i = tid; i < 1024; i += 512) FC1W[i] = p.WF[768 + i];
  if (tid < 64)               FC2W[tid]     = p.WF[1792 + tid];
  if (tid >= 64 && tid < 72)  FB1[tid - 64] = p.WF[1856 + tid - 64];
  if (tid >= 72 && tid < 80)  FB2[tid - 72] = p.WF[1864 + tid - 72];
  if (tid >= 80 && tid < 88)  OWp[tid - 80] = p.WF[1872 + tid - 80];
  if (tid == 88)              OBp[0]        = p.WF[1880];
  __syncthreads();

  if (tid < 256) {
    int row = tid >> 3, o = tid & 7;
    float s = FB1[o];
#pragma unroll 8
    for (int k = 0; k < 128; ++k) s += H2[row * 132 + k] * FC1W[o * 128 + k];
    X1[tid] = fmaxf(s, 0.0f);
  }
  __syncthreads();
  if (tid < 256) {
    int row = tid >> 3, o = tid & 7;
    float s = FB2[o];
#pragma unroll
    for (int k = 0; k < 8; ++k) s += X1[row * 8 + k] * FC2W[o * 8 + k];
    X2[tid] = fmaxf(s, 0.0f);
  }
  __syncthreads();
  if (tid < 32) {
    float s = OBp[0];
#pragma unroll
    for (int k = 0; k < 8; ++k) s += X2[tid * 8 + k] * OWp[k];
    p.out[b0 + tid] = s;
  }
}

extern "C" void kernel_launch(void* const* d_in, const int* in_sizes, int n_in,
                              void* d_out, int out_size, void* d_ws, size_t ws_size,
                              hipStream_t stream)
{
  (void)in_sizes; (void)n_in; (void)ws_size; (void)out_size;

  SampParams sp;
  const float** grp[12] = { sp.w1i, sp.w1h, sp.b1, sp.w2i, sp.w2h, sp.b2,
                            sp.f1w, sp.f1b, sp.f2w, sp.f2b, sp.ow, sp.ob };
  int idx = 1;
  for (int t = 0; t < 12; ++t)
    for (int j = 0; j < 3; ++j)
      grp[t][j] = (const float*)d_in[idx++];
  sp.W2S = (short*)d_ws;
  sp.W1G = (short*)((char*)d_ws + WS_W1G_OFF);
  sp.WF  = (float*)((char*)d_ws + WS_WF_OFF);

  LstmParams bp;
  bp.input = (const float*)d_in[0];
  bp.W2S = (const short*)d_ws;
  bp.W1G = (const short*)((char*)d_ws + WS_W1G_OFF);
  bp.WF  = (const float*)((char*)d_ws + WS_WF_OFF);
  bp.out = (float*)d_out;

  sample_kernel<<<dim3(68), dim3(256), 0, stream>>>(sp);
  blstm_kernel<<<dim3(256), dim3(512), 0, stream>>>(bp);
}